// Round 1
// baseline (1241.148 us; speedup 1.0000x reference)
//
#include <hip/hip_runtime.h>
#include <hip/hip_bf16.h>

#define N_NODES 100000
#define N_EDGES 1200000
#define EMB_DIM 256
#define HID_DIM 64
#define N_QUERY 8192

typedef __bf16 bf16x8 __attribute__((ext_vector_type(8)));
typedef float  f32x4  __attribute__((ext_vector_type(4)));

__device__ inline float bf2f(unsigned short u) {
    return __uint_as_float(((unsigned)u) << 16);
}

// ---------------------------------------------------------------------------
// Kernel 1: fused projection. xm[n][0..63] = emb[n]@Ws.T + bs (as bf16)
//                             xm[n][64..127] = emb[n]@Wn.T + bn (as bf16)
// Block: 256 threads = 4 waves; each wave computes 16 nodes x 128 outputs.
// W fragments pre-swizzled into LDS fragment-major (conflict-free b128 reads).
// A-fragments read directly from global (128B-coalesced per row, read once).
// ---------------------------------------------------------------------------
__global__ __launch_bounds__(256) void proj_kernel(
    const float* __restrict__ emb, const float* __restrict__ Ws,
    const float* __restrict__ bs, const float* __restrict__ Wn,
    const float* __restrict__ bn, unsigned short* __restrict__ xm)
{
    // 8 col-tiles x 8 k-steps x 64 lanes = 4096 fragments of 16B = 64KB
    __shared__ bf16x8 lds_w[4096];
    const int tid = threadIdx.x;

    for (int f = tid; f < 4096; f += 256) {
        int lane = f & 63, ks = (f >> 6) & 7, ct = f >> 9;
        int od = ct * 16 + (lane & 15);
        int k0 = ks * 32 + (lane >> 4) * 8;
        const float* wrow = (od < HID_DIM) ? (Ws + od * EMB_DIM + k0)
                                           : (Wn + (od - HID_DIM) * EMB_DIM + k0);
        bf16x8 v;
#pragma unroll
        for (int j = 0; j < 8; ++j) v[j] = (__bf16)wrow[j];
        lds_w[f] = v;
    }
    __syncthreads();

    const int wave = tid >> 6, lane = tid & 63;
    const long nodebase = (long)blockIdx.x * 64 + wave * 16;
    long node = nodebase + (lane & 15);
    const long nclamp = (node < N_NODES) ? node : (N_NODES - 1);
    const float* arow = emb + nclamp * EMB_DIM + (lane >> 4) * 8;

    f32x4 acc[8];
#pragma unroll
    for (int ct = 0; ct < 8; ++ct) acc[ct] = (f32x4){0.f, 0.f, 0.f, 0.f};

    for (int ks = 0; ks < 8; ++ks) {
        const float* ap = arow + ks * 32;
        bf16x8 a;
#pragma unroll
        for (int j = 0; j < 8; ++j) a[j] = (__bf16)ap[j];
#pragma unroll
        for (int ct = 0; ct < 8; ++ct) {
            bf16x8 b = lds_w[(ct * 8 + ks) * 64 + lane];
            acc[ct] = __builtin_amdgcn_mfma_f32_16x16x32_bf16(a, b, acc[ct], 0, 0, 0);
        }
    }

    // D layout: col = lane&15 (within col-tile), row = (lane>>4)*4 + reg (node)
    const int rbase = (lane >> 4) * 4;
#pragma unroll
    for (int ct = 0; ct < 8; ++ct) {
        int od = ct * 16 + (lane & 15);
        float bias = (od < HID_DIM) ? bs[od] : bn[od - HID_DIM];
#pragma unroll
        for (int r = 0; r < 4; ++r) {
            long n = nodebase + rbase + r;
            if (n < N_NODES) {
                float v = acc[ct][r] + bias;
                union { __bf16 b; unsigned short u; } cv;
                cv.b = (__bf16)v;
                xm[n * 128 + od] = cv.u;
            }
        }
    }
}

// ---------------------------------------------------------------------------
// Kernel 2: edge scatter. agg[dst] += edge_w * m[src]  (m = xm cols 64..127)
// 16 threads per edge, 4 dims each, fp32 global atomics.
// ---------------------------------------------------------------------------
__global__ __launch_bounds__(256) void scatter_kernel(
    const float* __restrict__ edge_w, const int* __restrict__ src,
    const int* __restrict__ dst, const unsigned short* __restrict__ xm,
    float* __restrict__ agg)
{
    int t = blockIdx.x * 256 + threadIdx.x;
    int e = t >> 4;
    if (e >= N_EDGES) return;
    int g = t & 15;
    int s = src[e];
    int d = dst[e];
    float w = edge_w[e];
    const ushort4 mv = *reinterpret_cast<const ushort4*>(
        xm + (long)s * 128 + 64 + g * 4);
    float* arow = agg + (long)d * 64 + g * 4;
    atomicAdd(arow + 0, w * bf2f(mv.x));
    atomicAdd(arow + 1, w * bf2f(mv.y));
    atomicAdd(arow + 2, w * bf2f(mv.z));
    atomicAdd(arow + 3, w * bf2f(mv.w));
}

// ---------------------------------------------------------------------------
// Kernel 3: readout. out[q] = relu(x[n] + agg[n]) . Wr + br
// One wave per query; lane = hidden dim; shuffle reduction.
// ---------------------------------------------------------------------------
__global__ __launch_bounds__(256) void readout_kernel(
    const int* __restrict__ query, const unsigned short* __restrict__ xm,
    const float* __restrict__ agg, const float* __restrict__ Wr,
    const float* __restrict__ br, float* __restrict__ out)
{
    int q = blockIdx.x * 4 + (threadIdx.x >> 6);
    int lane = threadIdx.x & 63;
    if (q >= N_QUERY) return;
    int n = query[q];
    float x = bf2f(xm[(long)n * 128 + lane]);
    float h = x + agg[(long)n * 64 + lane];
    h = fmaxf(h, 0.f);
    float v = h * Wr[lane];
#pragma unroll
    for (int off = 32; off; off >>= 1) v += __shfl_xor(v, off, 64);
    if (lane == 0) out[q] = v + br[0];
}

extern "C" void kernel_launch(void* const* d_in, const int* in_sizes, int n_in,
                              void* d_out, int out_size, void* d_ws, size_t ws_size,
                              hipStream_t stream) {
    const float* emb    = (const float*)d_in[0];
    const float* edge_w = (const float*)d_in[1];
    const float* Ws     = (const float*)d_in[2];
    const float* bs     = (const float*)d_in[3];
    const float* Wn     = (const float*)d_in[4];
    const float* bn     = (const float*)d_in[5];
    const float* Wr     = (const float*)d_in[6];
    const float* br     = (const float*)d_in[7];
    const int*   src    = (const int*)d_in[8];
    const int*   dst    = (const int*)d_in[9];
    const int*   query  = (const int*)d_in[10];
    float* out = (float*)d_out;

    char* ws = (char*)d_ws;
    unsigned short* xm  = (unsigned short*)ws;                       // [N][128] bf16, 25.6MB
    float*          agg = (float*)(ws + (size_t)N_NODES * 128 * 2);  // [N][64] f32, 25.6MB

    hipMemsetAsync(agg, 0, (size_t)N_NODES * HID_DIM * sizeof(float), stream);

    proj_kernel<<<(N_NODES + 63) / 64, 256, 0, stream>>>(emb, Ws, bs, Wn, bn, xm);
    scatter_kernel<<<(N_EDGES * 16 + 255) / 256, 256, 0, stream>>>(edge_w, src, dst, xm, agg);
    readout_kernel<<<(N_QUERY + 3) / 4, 256, 0, stream>>>(query, xm, agg, Wr, br, out);
}

// Round 3
// 550.694 us; speedup vs baseline: 2.2538x; 2.2538x over previous
//
#include <hip/hip_runtime.h>
#include <hip/hip_bf16.h>

#define N_NODES 100000
#define N_EDGES 1200000
#define EMB_DIM 256
#define HID_DIM 64
#define N_QUERY 8192

typedef __bf16 bf16x8 __attribute__((ext_vector_type(8)));
typedef float  f32x4  __attribute__((ext_vector_type(4)));

__device__ inline float bf2f(unsigned short u) {
    return __uint_as_float(((unsigned)u) << 16);
}

// ---------------------------------------------------------------------------
// Kernel 1: fused projection. xm[n][0..63] = emb[n]@Ws.T + bs (as bf16)
//                             xm[n][64..127] = emb[n]@Wn.T + bn (as bf16)
// Block: 256 threads = 4 waves; each wave computes 16 nodes x 128 outputs.
// ---------------------------------------------------------------------------
__global__ __launch_bounds__(256) void proj_kernel(
    const float* __restrict__ emb, const float* __restrict__ Ws,
    const float* __restrict__ bs, const float* __restrict__ Wn,
    const float* __restrict__ bn, unsigned short* __restrict__ xm)
{
    // 8 col-tiles x 8 k-steps x 64 lanes = 4096 fragments of 16B = 64KB
    __shared__ bf16x8 lds_w[4096];
    const int tid = threadIdx.x;

    for (int f = tid; f < 4096; f += 256) {
        int lane = f & 63, ks = (f >> 6) & 7, ct = f >> 9;
        int od = ct * 16 + (lane & 15);
        int k0 = ks * 32 + (lane >> 4) * 8;
        const float* wrow = (od < HID_DIM) ? (Ws + od * EMB_DIM + k0)
                                           : (Wn + (od - HID_DIM) * EMB_DIM + k0);
        bf16x8 v;
#pragma unroll
        for (int j = 0; j < 8; ++j) v[j] = (__bf16)wrow[j];
        lds_w[f] = v;
    }
    __syncthreads();

    const int wave = tid >> 6, lane = tid & 63;
    const long nodebase = (long)blockIdx.x * 64 + wave * 16;
    long node = nodebase + (lane & 15);
    const long nclamp = (node < N_NODES) ? node : (N_NODES - 1);
    const float* arow = emb + nclamp * EMB_DIM + (lane >> 4) * 8;

    f32x4 acc[8];
#pragma unroll
    for (int ct = 0; ct < 8; ++ct) acc[ct] = (f32x4){0.f, 0.f, 0.f, 0.f};

    for (int ks = 0; ks < 8; ++ks) {
        const float* ap = arow + ks * 32;
        bf16x8 a;
#pragma unroll
        for (int j = 0; j < 8; ++j) a[j] = (__bf16)ap[j];
#pragma unroll
        for (int ct = 0; ct < 8; ++ct) {
            bf16x8 b = lds_w[(ct * 8 + ks) * 64 + lane];
            acc[ct] = __builtin_amdgcn_mfma_f32_16x16x32_bf16(a, b, acc[ct], 0, 0, 0);
        }
    }

    const int rbase = (lane >> 4) * 4;
#pragma unroll
    for (int ct = 0; ct < 8; ++ct) {
        int od = ct * 16 + (lane & 15);
        float bias = (od < HID_DIM) ? bs[od] : bn[od - HID_DIM];
#pragma unroll
        for (int r = 0; r < 4; ++r) {
            long n = nodebase + rbase + r;
            if (n < N_NODES) {
                float v = acc[ct][r] + bias;
                union { __bf16 b; unsigned short u; } cv;
                cv.b = (__bf16)v;
                xm[n * 128 + od] = cv.u;
            }
        }
    }
}

// ---------------------------------------------------------------------------
// Kernel 2a: mark queried nodes.
// ---------------------------------------------------------------------------
__global__ __launch_bounds__(256) void flag_kernel(
    const int* __restrict__ query, unsigned char* __restrict__ qmask)
{
    int q = blockIdx.x * 256 + threadIdx.x;
    if (q < N_QUERY) qmask[query[q]] = 1;
}

// ---------------------------------------------------------------------------
// Kernel 2b: compact edges whose dst is queried into elist.
// ---------------------------------------------------------------------------
__global__ __launch_bounds__(256) void compact_kernel(
    const int* __restrict__ dst, const unsigned char* __restrict__ qmask,
    int* __restrict__ elist, int* __restrict__ counter)
{
    int e = blockIdx.x * 256 + threadIdx.x;
    if (e >= N_EDGES) return;
    if (qmask[dst[e]]) {
        int pos = atomicAdd(counter, 1);
        elist[pos] = e;
    }
}

// ---------------------------------------------------------------------------
// Kernel 2c: scatter only compacted edges. agg[dst] += edge_w * m[src]
// 16 threads per edge, 4 dims each, fp32 global atomics. Grid-stride over
// device-side count (grid is capture-static).
// ---------------------------------------------------------------------------
__global__ __launch_bounds__(256) void scatter_kernel(
    const int* __restrict__ counter, const int* __restrict__ elist,
    const float* __restrict__ edge_w, const int* __restrict__ src,
    const int* __restrict__ dst, const unsigned short* __restrict__ xm,
    float* __restrict__ agg)
{
    const int total = counter[0] * 16;
    for (int t = blockIdx.x * 256 + threadIdx.x; t < total;
         t += gridDim.x * 256) {
        int e = elist[t >> 4];
        int g = t & 15;
        int s = src[e];
        int d = dst[e];
        float w = edge_w[e];
        const ushort4 mv = *reinterpret_cast<const ushort4*>(
            xm + (long)s * 128 + 64 + g * 4);
        float* arow = agg + (long)d * 64 + g * 4;
        atomicAdd(arow + 0, w * bf2f(mv.x));
        atomicAdd(arow + 1, w * bf2f(mv.y));
        atomicAdd(arow + 2, w * bf2f(mv.z));
        atomicAdd(arow + 3, w * bf2f(mv.w));
    }
}

// ---------------------------------------------------------------------------
// Kernel 3: readout. out[q] = relu(x[n] + agg[n]) . Wr + br
// ---------------------------------------------------------------------------
__global__ __launch_bounds__(256) void readout_kernel(
    const int* __restrict__ query, const unsigned short* __restrict__ xm,
    const float* __restrict__ agg, const float* __restrict__ Wr,
    const float* __restrict__ br, float* __restrict__ out)
{
    int q = blockIdx.x * 4 + (threadIdx.x >> 6);
    int lane = threadIdx.x & 63;
    if (q >= N_QUERY) return;
    int n = query[q];
    float x = bf2f(xm[(long)n * 128 + lane]);
    float h = x + agg[(long)n * 64 + lane];
    h = fmaxf(h, 0.f);
    float v = h * Wr[lane];
#pragma unroll
    for (int off = 32; off; off >>= 1) v += __shfl_xor(v, off, 64);
    if (lane == 0) out[q] = v + br[0];
}

extern "C" void kernel_launch(void* const* d_in, const int* in_sizes, int n_in,
                              void* d_out, int out_size, void* d_ws, size_t ws_size,
                              hipStream_t stream) {
    const float* emb    = (const float*)d_in[0];
    const float* edge_w = (const float*)d_in[1];
    const float* Ws     = (const float*)d_in[2];
    const float* bs     = (const float*)d_in[3];
    const float* Wn     = (const float*)d_in[4];
    const float* bn     = (const float*)d_in[5];
    const float* Wr     = (const float*)d_in[6];
    const float* br     = (const float*)d_in[7];
    const int*   src    = (const int*)d_in[8];
    const int*   dst    = (const int*)d_in[9];
    const int*   query  = (const int*)d_in[10];
    float* out = (float*)d_out;

    char* ws = (char*)d_ws;
    size_t off = 0;
    unsigned short* xm = (unsigned short*)(ws + off);
    off += (size_t)N_NODES * 128 * 2;                 // 25.6 MB
    float* agg = (float*)(ws + off);
    off += (size_t)N_NODES * HID_DIM * sizeof(float); // 25.6 MB
    unsigned char* qmask = (unsigned char*)(ws + off);
    off += (N_NODES + 256) & ~255;                    // 100 KB
    int* elist = (int*)(ws + off);
    off += (size_t)N_EDGES * sizeof(int);             // 4.8 MB
    int* counter = (int*)(ws + off);
    off += 256;

    hipMemsetAsync(agg, 0, (size_t)N_NODES * HID_DIM * sizeof(float), stream);
    hipMemsetAsync(qmask, 0, N_NODES, stream);
    hipMemsetAsync(counter, 0, sizeof(int), stream);

    proj_kernel<<<(N_NODES + 63) / 64, 256, 0, stream>>>(emb, Ws, bs, Wn, bn, xm);
    flag_kernel<<<(N_QUERY + 255) / 256, 256, 0, stream>>>(query, qmask);
    compact_kernel<<<(N_EDGES + 255) / 256, 256, 0, stream>>>(dst, qmask, elist, counter);
    scatter_kernel<<<2048, 256, 0, stream>>>(counter, elist, edge_w, src, dst, xm, agg);
    readout_kernel<<<(N_QUERY + 3) / 4, 256, 0, stream>>>(query, xm, agg, Wr, br, out);
}

// Round 4
// 339.836 us; speedup vs baseline: 3.6522x; 1.6205x over previous
//
#include <hip/hip_runtime.h>
#include <hip/hip_bf16.h>

#define N_NODES 100000
#define N_EDGES 1200000
#define EMB_DIM 256
#define HID_DIM 64
#define N_QUERY 8192

typedef __bf16 bf16x8 __attribute__((ext_vector_type(8)));
typedef float  f32x4  __attribute__((ext_vector_type(4)));

__device__ inline float bf2f(unsigned short u) {
    return __uint_as_float(((unsigned)u) << 16);
}

// ---------------------------------------------------------------------------
// Kernel 1: fused projection. xm[n][0..63] = emb[n]@Ws.T + bs (as bf16)
//                             xm[n][64..127] = emb[n]@Wn.T + bn (as bf16)
// Block: 256 threads = 4 waves; each wave computes 16 nodes x 128 outputs.
// ---------------------------------------------------------------------------
__global__ __launch_bounds__(256) void proj_kernel(
    const float* __restrict__ emb, const float* __restrict__ Ws,
    const float* __restrict__ bs, const float* __restrict__ Wn,
    const float* __restrict__ bn, unsigned short* __restrict__ xm)
{
    // 8 col-tiles x 8 k-steps x 64 lanes = 4096 fragments of 16B = 64KB
    __shared__ bf16x8 lds_w[4096];
    const int tid = threadIdx.x;

    for (int f = tid; f < 4096; f += 256) {
        int lane = f & 63, ks = (f >> 6) & 7, ct = f >> 9;
        int od = ct * 16 + (lane & 15);
        int k0 = ks * 32 + (lane >> 4) * 8;
        const float* wrow = (od < HID_DIM) ? (Ws + od * EMB_DIM + k0)
                                           : (Wn + (od - HID_DIM) * EMB_DIM + k0);
        bf16x8 v;
#pragma unroll
        for (int j = 0; j < 8; ++j) v[j] = (__bf16)wrow[j];
        lds_w[f] = v;
    }
    __syncthreads();

    const int wave = tid >> 6, lane = tid & 63;
    const long nodebase = (long)blockIdx.x * 64 + wave * 16;
    long node = nodebase + (lane & 15);
    const long nclamp = (node < N_NODES) ? node : (N_NODES - 1);
    const float* arow = emb + nclamp * EMB_DIM + (lane >> 4) * 8;

    f32x4 acc[8];
#pragma unroll
    for (int ct = 0; ct < 8; ++ct) acc[ct] = (f32x4){0.f, 0.f, 0.f, 0.f};

    for (int ks = 0; ks < 8; ++ks) {
        const float* ap = arow + ks * 32;
        bf16x8 a;
#pragma unroll
        for (int j = 0; j < 8; ++j) a[j] = (__bf16)ap[j];
#pragma unroll
        for (int ct = 0; ct < 8; ++ct) {
            bf16x8 b = lds_w[(ct * 8 + ks) * 64 + lane];
            acc[ct] = __builtin_amdgcn_mfma_f32_16x16x32_bf16(a, b, acc[ct], 0, 0, 0);
        }
    }

    const int rbase = (lane >> 4) * 4;
#pragma unroll
    for (int ct = 0; ct < 8; ++ct) {
        int od = ct * 16 + (lane & 15);
        float bias = (od < HID_DIM) ? bs[od] : bn[od - HID_DIM];
#pragma unroll
        for (int r = 0; r < 4; ++r) {
            long n = nodebase + rbase + r;
            if (n < N_NODES) {
                float v = acc[ct][r] + bias;
                union { __bf16 b; unsigned short u; } cv;
                cv.b = (__bf16)v;
                xm[n * 128 + od] = cv.u;
            }
        }
    }
}

// ---------------------------------------------------------------------------
// Kernel 2a: mark queried nodes.
// ---------------------------------------------------------------------------
__global__ __launch_bounds__(256) void flag_kernel(
    const int* __restrict__ query, unsigned char* __restrict__ qmask)
{
    int q = blockIdx.x * 256 + threadIdx.x;
    if (q < N_QUERY) qmask[query[q]] = 1;
}

// ---------------------------------------------------------------------------
// Kernel 2b: fused mask-check + scatter. For edges whose dst is queried:
//   agg[dst] += edge_w * m[src]   (m = xm cols 64..127)
// 16 threads per edge, 4 dims each. No compaction list, no global counter —
// threads for non-hit edges exit after two L2-resident loads (~92% of edges).
// ---------------------------------------------------------------------------
__global__ __launch_bounds__(256) void scatter_kernel(
    const float* __restrict__ edge_w, const int* __restrict__ src,
    const int* __restrict__ dst, const unsigned char* __restrict__ qmask,
    const unsigned short* __restrict__ xm, float* __restrict__ agg)
{
    int t = blockIdx.x * 256 + threadIdx.x;
    int e = t >> 4;
    if (e >= N_EDGES) return;
    int d = dst[e];
    if (!qmask[d]) return;
    int g = t & 15;
    int s = src[e];
    float w = edge_w[e];
    const ushort4 mv = *reinterpret_cast<const ushort4*>(
        xm + (long)s * 128 + 64 + g * 4);
    float* arow = agg + (long)d * 64 + g * 4;
    atomicAdd(arow + 0, w * bf2f(mv.x));
    atomicAdd(arow + 1, w * bf2f(mv.y));
    atomicAdd(arow + 2, w * bf2f(mv.z));
    atomicAdd(arow + 3, w * bf2f(mv.w));
}

// ---------------------------------------------------------------------------
// Kernel 3: readout. out[q] = relu(x[n] + agg[n]) . Wr + br
// ---------------------------------------------------------------------------
__global__ __launch_bounds__(256) void readout_kernel(
    const int* __restrict__ query, const unsigned short* __restrict__ xm,
    const float* __restrict__ agg, const float* __restrict__ Wr,
    const float* __restrict__ br, float* __restrict__ out)
{
    int q = blockIdx.x * 4 + (threadIdx.x >> 6);
    int lane = threadIdx.x & 63;
    if (q >= N_QUERY) return;
    int n = query[q];
    float x = bf2f(xm[(long)n * 128 + lane]);
    float h = x + agg[(long)n * 64 + lane];
    h = fmaxf(h, 0.f);
    float v = h * Wr[lane];
#pragma unroll
    for (int off = 32; off; off >>= 1) v += __shfl_xor(v, off, 64);
    if (lane == 0) out[q] = v + br[0];
}

extern "C" void kernel_launch(void* const* d_in, const int* in_sizes, int n_in,
                              void* d_out, int out_size, void* d_ws, size_t ws_size,
                              hipStream_t stream) {
    const float* emb    = (const float*)d_in[0];
    const float* edge_w = (const float*)d_in[1];
    const float* Ws     = (const float*)d_in[2];
    const float* bs     = (const float*)d_in[3];
    const float* Wn     = (const float*)d_in[4];
    const float* bn     = (const float*)d_in[5];
    const float* Wr     = (const float*)d_in[6];
    const float* br     = (const float*)d_in[7];
    const int*   src    = (const int*)d_in[8];
    const int*   dst    = (const int*)d_in[9];
    const int*   query  = (const int*)d_in[10];
    float* out = (float*)d_out;

    char* ws = (char*)d_ws;
    size_t off = 0;
    unsigned short* xm = (unsigned short*)(ws + off);
    off += (size_t)N_NODES * 128 * 2;                 // 25.6 MB
    float* agg = (float*)(ws + off);
    off += (size_t)N_NODES * HID_DIM * sizeof(float); // 25.6 MB
    unsigned char* qmask = (unsigned char*)(ws + off);
    off += (N_NODES + 256) & ~255;                    // 100 KB

    hipMemsetAsync(agg, 0, (size_t)N_NODES * HID_DIM * sizeof(float), stream);
    hipMemsetAsync(qmask, 0, N_NODES, stream);

    proj_kernel<<<(N_NODES + 63) / 64, 256, 0, stream>>>(emb, Ws, bs, Wn, bn, xm);
    flag_kernel<<<(N_QUERY + 255) / 256, 256, 0, stream>>>(query, qmask);
    scatter_kernel<<<(N_EDGES * 16 + 255) / 256, 256, 0, stream>>>(
        edge_w, src, dst, qmask, xm, agg);
    readout_kernel<<<(N_QUERY + 3) / 4, 256, 0, stream>>>(query, xm, agg, Wr, br, out);
}

// Round 5
// 263.296 us; speedup vs baseline: 4.7139x; 1.2907x over previous
//
#include <hip/hip_runtime.h>
#include <hip/hip_bf16.h>

#define N_NODES 100000
#define N_EDGES 1200000
#define EMB_DIM 256
#define HID_DIM 64
#define N_QUERY 8192
#define N_PAD 100096          // N_NODES padded to 256 multiple (391 blocks)
#define SCAN_BLOCKS 391

typedef __bf16 bf16x8 __attribute__((ext_vector_type(8)));
typedef float  f32x4  __attribute__((ext_vector_type(4)));

__device__ inline float bf2f(unsigned short u) {
    return __uint_as_float(((unsigned)u) << 16);
}

// ---------------------------------------------------------------------------
// Kernel 1: fused projection. xm[n][0..63] = emb[n]@Ws.T + bs (as bf16)
//                             xm[n][64..127] = emb[n]@Wn.T + bn (as bf16)
// Block: 256 threads = 4 waves; each wave computes 16 nodes x 128 outputs.
// ---------------------------------------------------------------------------
__global__ __launch_bounds__(256) void proj_kernel(
    const float* __restrict__ emb, const float* __restrict__ Ws,
    const float* __restrict__ bs, const float* __restrict__ Wn,
    const float* __restrict__ bn, unsigned short* __restrict__ xm)
{
    // 8 col-tiles x 8 k-steps x 64 lanes = 4096 fragments of 16B = 64KB
    __shared__ bf16x8 lds_w[4096];
    const int tid = threadIdx.x;

    for (int f = tid; f < 4096; f += 256) {
        int lane = f & 63, ks = (f >> 6) & 7, ct = f >> 9;
        int od = ct * 16 + (lane & 15);
        int k0 = ks * 32 + (lane >> 4) * 8;
        const float* wrow = (od < HID_DIM) ? (Ws + od * EMB_DIM + k0)
                                           : (Wn + (od - HID_DIM) * EMB_DIM + k0);
        const f32x4 lo = *reinterpret_cast<const f32x4*>(wrow);
        const f32x4 hi = *reinterpret_cast<const f32x4*>(wrow + 4);
        bf16x8 v;
#pragma unroll
        for (int j = 0; j < 4; ++j) { v[j] = (__bf16)lo[j]; v[j+4] = (__bf16)hi[j]; }
        lds_w[f] = v;
    }
    __syncthreads();

    const int wave = tid >> 6, lane = tid & 63;
    const long nodebase = (long)blockIdx.x * 64 + wave * 16;
    long node = nodebase + (lane & 15);
    const long nclamp = (node < N_NODES) ? node : (N_NODES - 1);
    const float* arow = emb + nclamp * EMB_DIM + (lane >> 4) * 8;

    f32x4 acc[8];
#pragma unroll
    for (int ct = 0; ct < 8; ++ct) acc[ct] = (f32x4){0.f, 0.f, 0.f, 0.f};

#pragma unroll
    for (int ks = 0; ks < 8; ++ks) {
        const float* ap = arow + ks * 32;
        const f32x4 lo = *reinterpret_cast<const f32x4*>(ap);
        const f32x4 hi = *reinterpret_cast<const f32x4*>(ap + 4);
        bf16x8 a;
#pragma unroll
        for (int j = 0; j < 4; ++j) { a[j] = (__bf16)lo[j]; a[j+4] = (__bf16)hi[j]; }
#pragma unroll
        for (int ct = 0; ct < 8; ++ct) {
            bf16x8 b = lds_w[(ct * 8 + ks) * 64 + lane];
            acc[ct] = __builtin_amdgcn_mfma_f32_16x16x32_bf16(a, b, acc[ct], 0, 0, 0);
        }
    }

    const int rbase = (lane >> 4) * 4;
#pragma unroll
    for (int ct = 0; ct < 8; ++ct) {
        int od = ct * 16 + (lane & 15);
        float bias = (od < HID_DIM) ? bs[od] : bn[od - HID_DIM];
#pragma unroll
        for (int r = 0; r < 4; ++r) {
            long n = nodebase + rbase + r;
            if (n < N_NODES) {
                float v = acc[ct][r] + bias;
                union { __bf16 b; unsigned short u; } cv;
                cv.b = (__bf16)v;
                xm[n * 128 + od] = cv.u;
            }
        }
    }
}

// ---------------------------------------------------------------------------
// Kernel 2: mark queried nodes.
// ---------------------------------------------------------------------------
__global__ __launch_bounds__(256) void flag_kernel(
    const int* __restrict__ query, unsigned char* __restrict__ qmask)
{
    int q = blockIdx.x * 256 + threadIdx.x;
    if (q < N_QUERY) qmask[query[q]] = 1;
}

// ---------------------------------------------------------------------------
// Kernel 3: in-degree count of queried nodes (~94.5K atomics total).
// ---------------------------------------------------------------------------
__global__ __launch_bounds__(256) void count_kernel(
    const int* __restrict__ dst, const unsigned char* __restrict__ qmask,
    int* __restrict__ deg)
{
    int e = blockIdx.x * 256 + threadIdx.x;
    if (e >= N_EDGES) return;
    int d = dst[e];
    if (qmask[d]) atomicAdd(&deg[d], 1);
}

// ---------------------------------------------------------------------------
// Kernel 4a: per-block exclusive scan of deg -> offs, block totals -> bsum.
// ---------------------------------------------------------------------------
__global__ __launch_bounds__(256) void scan1_kernel(
    const int* __restrict__ deg, int* __restrict__ offs, int* __restrict__ bsum)
{
    __shared__ int s[256];
    int tid = threadIdx.x;
    int i = blockIdx.x * 256 + tid;
    int v = (i < N_NODES) ? deg[i] : 0;
    s[tid] = v;
    __syncthreads();
#pragma unroll
    for (int d = 1; d < 256; d <<= 1) {
        int t = (tid >= d) ? s[tid - d] : 0;
        __syncthreads();
        s[tid] += t;
        __syncthreads();
    }
    offs[i] = s[tid] - v;                       // exclusive
    if (tid == 255) bsum[blockIdx.x] = s[tid];  // block total
}

// ---------------------------------------------------------------------------
// Kernel 4b: exclusive scan of the 391 block totals (single block, 512 thr).
// ---------------------------------------------------------------------------
__global__ __launch_bounds__(512) void scan2_kernel(int* __restrict__ bsum)
{
    __shared__ int s[512];
    int tid = threadIdx.x;
    int v = (tid < SCAN_BLOCKS) ? bsum[tid] : 0;
    s[tid] = v;
    __syncthreads();
#pragma unroll
    for (int d = 1; d < 512; d <<= 1) {
        int t = (tid >= d) ? s[tid - d] : 0;
        __syncthreads();
        s[tid] += t;
        __syncthreads();
    }
    bsum[tid] = s[tid] - v;                     // exclusive
}

// ---------------------------------------------------------------------------
// Kernel 5: fill CSR pair list. pairs[base + k] = {src, bits(w)}
// base = offs[d] + bsum[d>>8] (add-back fused), k = per-node cursor.
// ---------------------------------------------------------------------------
__global__ __launch_bounds__(256) void fill_kernel(
    const int* __restrict__ dst, const int* __restrict__ src,
    const float* __restrict__ edge_w, const unsigned char* __restrict__ qmask,
    const int* __restrict__ offs, const int* __restrict__ bsum,
    int* __restrict__ cursor, int2* __restrict__ pairs)
{
    int e = blockIdx.x * 256 + threadIdx.x;
    if (e >= N_EDGES) return;
    int d = dst[e];
    if (!qmask[d]) return;
    int k = atomicAdd(&cursor[d], 1);
    int pos = offs[d] + bsum[d >> 8] + k;
    pairs[pos] = make_int2(src[e], __float_as_int(edge_w[e]));
}

// ---------------------------------------------------------------------------
// Kernel 6: fused gather + readout. One wave per query:
//   out[q] = relu(x[n] + sum_e w_e * m[src_e]) . Wr + br
// 4 edges in flight (16 lanes each, lane i -> dims 4i..4i+3 via ushort4).
// Zero atomics; duplicate queries just recompute (writes to distinct out[q]).
// ---------------------------------------------------------------------------
__global__ __launch_bounds__(256) void gather_readout_kernel(
    const int* __restrict__ query, const int* __restrict__ deg,
    const int* __restrict__ offs, const int* __restrict__ bsum,
    const int2* __restrict__ pairs, const unsigned short* __restrict__ xm,
    const float* __restrict__ Wr, const float* __restrict__ br,
    float* __restrict__ out)
{
    int q = blockIdx.x * 4 + (threadIdx.x >> 6);
    if (q >= N_QUERY) return;
    int lane = threadIdx.x & 63;
    int g = lane >> 4, i = lane & 15;

    int n = query[q];
    int start = offs[n] + bsum[n >> 8];
    int cnt = deg[n];

    f32x4 acc = (f32x4){0.f, 0.f, 0.f, 0.f};
    for (int k = g; k < cnt; k += 4) {
        int2 pr = pairs[start + k];            // uniform within 16-lane group
        float w = __int_as_float(pr.y);
        const ushort4 mv = *reinterpret_cast<const ushort4*>(
            xm + (long)pr.x * 128 + 64 + i * 4);
        acc[0] += w * bf2f(mv.x);
        acc[1] += w * bf2f(mv.y);
        acc[2] += w * bf2f(mv.z);
        acc[3] += w * bf2f(mv.w);
    }
    // reduce the 4 edge-groups (lane-xor over bits 4 and 5)
#pragma unroll
    for (int j = 0; j < 4; ++j) {
        acc[j] += __shfl_xor(acc[j], 16, 64);
        acc[j] += __shfl_xor(acc[j], 32, 64);
    }
    // x + relu + dot(Wr)
    const ushort4 xv = *reinterpret_cast<const ushort4*>(xm + (long)n * 128 + i * 4);
    const f32x4 wr = *reinterpret_cast<const f32x4*>(Wr + i * 4);
    float s = fmaxf(bf2f(xv.x) + acc[0], 0.f) * wr[0]
            + fmaxf(bf2f(xv.y) + acc[1], 0.f) * wr[1]
            + fmaxf(bf2f(xv.z) + acc[2], 0.f) * wr[2]
            + fmaxf(bf2f(xv.w) + acc[3], 0.f) * wr[3];
#pragma unroll
    for (int off = 8; off; off >>= 1) s += __shfl_xor(s, off, 64);
    if (lane == 0) out[q] = s + br[0];
}

extern "C" void kernel_launch(void* const* d_in, const int* in_sizes, int n_in,
                              void* d_out, int out_size, void* d_ws, size_t ws_size,
                              hipStream_t stream) {
    const float* emb    = (const float*)d_in[0];
    const float* edge_w = (const float*)d_in[1];
    const float* Ws     = (const float*)d_in[2];
    const float* bs     = (const float*)d_in[3];
    const float* Wn     = (const float*)d_in[4];
    const float* bn     = (const float*)d_in[5];
    const float* Wr     = (const float*)d_in[6];
    const float* br     = (const float*)d_in[7];
    const int*   src    = (const int*)d_in[8];
    const int*   dst    = (const int*)d_in[9];
    const int*   query  = (const int*)d_in[10];
    float* out = (float*)d_out;

    char* ws = (char*)d_ws;
    size_t off = 0;
    unsigned short* xm = (unsigned short*)(ws + off);
    off += (size_t)N_NODES * 128 * 2;          // 25.6 MB (256-aligned)
    // --- one contiguous memset region: deg, cursor, qmask ---
    int* deg = (int*)(ws + off);
    size_t zero_base = off;
    off += (size_t)N_PAD * 4;                  // 400,384 B
    int* cursor = (int*)(ws + off);
    off += (size_t)N_PAD * 4;                  // 400,384 B
    unsigned char* qmask = (unsigned char*)(ws + off);
    off += 100352;                             // N_PAD padded to 256 B
    size_t zero_len = off - zero_base;
    // --- scan outputs (fully written before read) ---
    int* offs = (int*)(ws + off);
    off += (size_t)N_PAD * 4;
    int* bsum = (int*)(ws + off);
    off += 512 * 4;
    int2* pairs = (int2*)(ws + off);
    off += (size_t)N_EDGES * 8;                // 9.6 MB worst case

    hipMemsetAsync(ws + zero_base, 0, zero_len, stream);

    proj_kernel<<<(N_NODES + 63) / 64, 256, 0, stream>>>(emb, Ws, bs, Wn, bn, xm);
    flag_kernel<<<(N_QUERY + 255) / 256, 256, 0, stream>>>(query, qmask);
    count_kernel<<<(N_EDGES + 255) / 256, 256, 0, stream>>>(dst, qmask, deg);
    scan1_kernel<<<SCAN_BLOCKS, 256, 0, stream>>>(deg, offs, bsum);
    scan2_kernel<<<1, 512, 0, stream>>>(bsum);
    fill_kernel<<<(N_EDGES + 255) / 256, 256, 0, stream>>>(
        dst, src, edge_w, qmask, offs, bsum, cursor, pairs);
    gather_readout_kernel<<<(N_QUERY + 3) / 4, 256, 0, stream>>>(
        query, deg, offs, bsum, pairs, xm, Wr, br, out);
}

// Round 6
// 236.705 us; speedup vs baseline: 5.2434x; 1.1123x over previous
//
#include <hip/hip_runtime.h>
#include <hip/hip_bf16.h>

#define N_NODES 100000
#define N_EDGES 1200000
#define EMB_DIM 256
#define HID_DIM 64
#define N_QUERY 8192
#define N_PAD 100096          // N_NODES padded to 256 multiple (391 blocks)
#define SCAN_BLOCKS 391

typedef __bf16 bf16x8 __attribute__((ext_vector_type(8)));
typedef float  f32x4  __attribute__((ext_vector_type(4)));

__device__ inline float bf2f(unsigned short u) {
    return __uint_as_float(((unsigned)u) << 16);
}

// ---------------------------------------------------------------------------
// Kernel 1: fused projection. xm[n][0..63] = emb[n]@Ws.T + bs (as bf16)
//                             xm[n][64..127] = emb[n]@Wn.T + bn (as bf16)
// Block: 512 threads = 8 waves; each wave computes 16 nodes x 128 outputs.
// 64KB weight-LDS shared by 8 waves; 2 blocks/CU -> 16 waves/CU (VGPR<=128).
// All 16 A-loads hoisted per tile for memory-level parallelism.
// ---------------------------------------------------------------------------
__global__ __launch_bounds__(512) void proj_kernel(
    const float* __restrict__ emb, const float* __restrict__ Ws,
    const float* __restrict__ bs, const float* __restrict__ Wn,
    const float* __restrict__ bn, unsigned short* __restrict__ xm)
{
    // 8 col-tiles x 8 k-steps x 64 lanes = 4096 fragments of 16B = 64KB
    __shared__ bf16x8 lds_w[4096];
    const int tid = threadIdx.x;

    for (int f = tid; f < 4096; f += 512) {
        int lane = f & 63, ks = (f >> 6) & 7, ct = f >> 9;
        int od = ct * 16 + (lane & 15);
        int k0 = ks * 32 + (lane >> 4) * 8;
        const float* wrow = (od < HID_DIM) ? (Ws + od * EMB_DIM + k0)
                                           : (Wn + (od - HID_DIM) * EMB_DIM + k0);
        const f32x4 lo = *reinterpret_cast<const f32x4*>(wrow);
        const f32x4 hi = *reinterpret_cast<const f32x4*>(wrow + 4);
        bf16x8 v;
#pragma unroll
        for (int j = 0; j < 4; ++j) { v[j] = (__bf16)lo[j]; v[j+4] = (__bf16)hi[j]; }
        lds_w[f] = v;
    }
    __syncthreads();

    const int wave = tid >> 6, lane = tid & 63;
    const long nodebase = (long)blockIdx.x * 128 + wave * 16;
    long node = nodebase + (lane & 15);
    const long nclamp = (node < N_NODES) ? node : (N_NODES - 1);
    const float* arow = emb + nclamp * EMB_DIM + (lane >> 4) * 8;

    // Hoist all A loads for this tile: 8 k-steps x 32B/lane = 16 dwordx4.
    f32x4 a_lo[8], a_hi[8];
#pragma unroll
    for (int ks = 0; ks < 8; ++ks) {
        a_lo[ks] = *reinterpret_cast<const f32x4*>(arow + ks * 32);
        a_hi[ks] = *reinterpret_cast<const f32x4*>(arow + ks * 32 + 4);
    }

    f32x4 acc[8];
#pragma unroll
    for (int ct = 0; ct < 8; ++ct) acc[ct] = (f32x4){0.f, 0.f, 0.f, 0.f};

#pragma unroll
    for (int ks = 0; ks < 8; ++ks) {
        bf16x8 a;
#pragma unroll
        for (int j = 0; j < 4; ++j) {
            a[j]     = (__bf16)a_lo[ks][j];
            a[j + 4] = (__bf16)a_hi[ks][j];
        }
#pragma unroll
        for (int ct = 0; ct < 8; ++ct) {
            bf16x8 b = lds_w[(ct * 8 + ks) * 64 + lane];
            acc[ct] = __builtin_amdgcn_mfma_f32_16x16x32_bf16(a, b, acc[ct], 0, 0, 0);
        }
    }

    const int rbase = (lane >> 4) * 4;
#pragma unroll
    for (int ct = 0; ct < 8; ++ct) {
        int od = ct * 16 + (lane & 15);
        float bias = (od < HID_DIM) ? bs[od] : bn[od - HID_DIM];
#pragma unroll
        for (int r = 0; r < 4; ++r) {
            long n = nodebase + rbase + r;
            if (n < N_NODES) {
                float v = acc[ct][r] + bias;
                union { __bf16 b; unsigned short u; } cv;
                cv.b = (__bf16)v;
                xm[n * 128 + od] = cv.u;
            }
        }
    }
}

// ---------------------------------------------------------------------------
// Kernel 2: mark queried nodes.
// ---------------------------------------------------------------------------
__global__ __launch_bounds__(256) void flag_kernel(
    const int* __restrict__ query, unsigned char* __restrict__ qmask)
{
    int q = blockIdx.x * 256 + threadIdx.x;
    if (q < N_QUERY) qmask[query[q]] = 1;
}

// ---------------------------------------------------------------------------
// Kernel 3: in-degree count of queried nodes (~94.5K atomics total).
// ---------------------------------------------------------------------------
__global__ __launch_bounds__(256) void count_kernel(
    const int* __restrict__ dst, const unsigned char* __restrict__ qmask,
    int* __restrict__ deg)
{
    int e = blockIdx.x * 256 + threadIdx.x;
    if (e >= N_EDGES) return;
    int d = dst[e];
    if (qmask[d]) atomicAdd(&deg[d], 1);
}

// ---------------------------------------------------------------------------
// Kernel 4a: per-block exclusive scan of deg -> offs, block totals -> bsum.
// ---------------------------------------------------------------------------
__global__ __launch_bounds__(256) void scan1_kernel(
    const int* __restrict__ deg, int* __restrict__ offs, int* __restrict__ bsum)
{
    __shared__ int s[256];
    int tid = threadIdx.x;
    int i = blockIdx.x * 256 + tid;
    int v = (i < N_NODES) ? deg[i] : 0;
    s[tid] = v;
    __syncthreads();
#pragma unroll
    for (int d = 1; d < 256; d <<= 1) {
        int t = (tid >= d) ? s[tid - d] : 0;
        __syncthreads();
        s[tid] += t;
        __syncthreads();
    }
    offs[i] = s[tid] - v;                       // exclusive
    if (tid == 255) bsum[blockIdx.x] = s[tid];  // block total
}

// ---------------------------------------------------------------------------
// Kernel 4b: exclusive scan of the 391 block totals (single block, 512 thr).
// ---------------------------------------------------------------------------
__global__ __launch_bounds__(512) void scan2_kernel(int* __restrict__ bsum)
{
    __shared__ int s[512];
    int tid = threadIdx.x;
    int v = (tid < SCAN_BLOCKS) ? bsum[tid] : 0;
    s[tid] = v;
    __syncthreads();
#pragma unroll
    for (int d = 1; d < 512; d <<= 1) {
        int t = (tid >= d) ? s[tid - d] : 0;
        __syncthreads();
        s[tid] += t;
        __syncthreads();
    }
    bsum[tid] = s[tid] - v;                     // exclusive
}

// ---------------------------------------------------------------------------
// Kernel 5: fill CSR pair list. pairs[base + k] = {src, bits(w)}
// base = offs[d] + bsum[d>>8] (add-back fused), k = per-node cursor.
// ---------------------------------------------------------------------------
__global__ __launch_bounds__(256) void fill_kernel(
    const int* __restrict__ dst, const int* __restrict__ src,
    const float* __restrict__ edge_w, const unsigned char* __restrict__ qmask,
    const int* __restrict__ offs, const int* __restrict__ bsum,
    int* __restrict__ cursor, int2* __restrict__ pairs)
{
    int e = blockIdx.x * 256 + threadIdx.x;
    if (e >= N_EDGES) return;
    int d = dst[e];
    if (!qmask[d]) return;
    int k = atomicAdd(&cursor[d], 1);
    int pos = offs[d] + bsum[d >> 8] + k;
    pairs[pos] = make_int2(src[e], __float_as_int(edge_w[e]));
}

// ---------------------------------------------------------------------------
// Kernel 6: fused gather + readout. One wave per query:
//   out[q] = relu(x[n] + sum_e w_e * m[src_e]) . Wr + br
// 4 edges in flight (16 lanes each, lane i -> dims 4i..4i+3 via ushort4).
// ---------------------------------------------------------------------------
__global__ __launch_bounds__(256) void gather_readout_kernel(
    const int* __restrict__ query, const int* __restrict__ deg,
    const int* __restrict__ offs, const int* __restrict__ bsum,
    const int2* __restrict__ pairs, const unsigned short* __restrict__ xm,
    const float* __restrict__ Wr, const float* __restrict__ br,
    float* __restrict__ out)
{
    int q = blockIdx.x * 4 + (threadIdx.x >> 6);
    if (q >= N_QUERY) return;
    int lane = threadIdx.x & 63;
    int g = lane >> 4, i = lane & 15;

    int n = query[q];
    int start = offs[n] + bsum[n >> 8];
    int cnt = deg[n];

    f32x4 acc = (f32x4){0.f, 0.f, 0.f, 0.f};
    for (int k = g; k < cnt; k += 4) {
        int2 pr = pairs[start + k];            // uniform within 16-lane group
        float w = __int_as_float(pr.y);
        const ushort4 mv = *reinterpret_cast<const ushort4*>(
            xm + (long)pr.x * 128 + 64 + i * 4);
        acc[0] += w * bf2f(mv.x);
        acc[1] += w * bf2f(mv.y);
        acc[2] += w * bf2f(mv.z);
        acc[3] += w * bf2f(mv.w);
    }
#pragma unroll
    for (int j = 0; j < 4; ++j) {
        acc[j] += __shfl_xor(acc[j], 16, 64);
        acc[j] += __shfl_xor(acc[j], 32, 64);
    }
    const ushort4 xv = *reinterpret_cast<const ushort4*>(xm + (long)n * 128 + i * 4);
    const f32x4 wr = *reinterpret_cast<const f32x4*>(Wr + i * 4);
    float s = fmaxf(bf2f(xv.x) + acc[0], 0.f) * wr[0]
            + fmaxf(bf2f(xv.y) + acc[1], 0.f) * wr[1]
            + fmaxf(bf2f(xv.z) + acc[2], 0.f) * wr[2]
            + fmaxf(bf2f(xv.w) + acc[3], 0.f) * wr[3];
#pragma unroll
    for (int off = 8; off; off >>= 1) s += __shfl_xor(s, off, 64);
    if (lane == 0) out[q] = s + br[0];
}

extern "C" void kernel_launch(void* const* d_in, const int* in_sizes, int n_in,
                              void* d_out, int out_size, void* d_ws, size_t ws_size,
                              hipStream_t stream) {
    const float* emb    = (const float*)d_in[0];
    const float* edge_w = (const float*)d_in[1];
    const float* Ws     = (const float*)d_in[2];
    const float* bs     = (const float*)d_in[3];
    const float* Wn     = (const float*)d_in[4];
    const float* bn     = (const float*)d_in[5];
    const float* Wr     = (const float*)d_in[6];
    const float* br     = (const float*)d_in[7];
    const int*   src    = (const int*)d_in[8];
    const int*   dst    = (const int*)d_in[9];
    const int*   query  = (const int*)d_in[10];
    float* out = (float*)d_out;

    char* ws = (char*)d_ws;
    size_t off = 0;
    unsigned short* xm = (unsigned short*)(ws + off);
    off += (size_t)N_NODES * 128 * 2;          // 25.6 MB (256-aligned)
    // --- one contiguous memset region: deg, cursor, qmask ---
    int* deg = (int*)(ws + off);
    size_t zero_base = off;
    off += (size_t)N_PAD * 4;                  // 400,384 B
    int* cursor = (int*)(ws + off);
    off += (size_t)N_PAD * 4;                  // 400,384 B
    unsigned char* qmask = (unsigned char*)(ws + off);
    off += 100352;                             // N_PAD padded to 256 B
    size_t zero_len = off - zero_base;
    // --- scan outputs (fully written before read) ---
    int* offs = (int*)(ws + off);
    off += (size_t)N_PAD * 4;
    int* bsum = (int*)(ws + off);
    off += 512 * 4;
    int2* pairs = (int2*)(ws + off);
    off += (size_t)N_EDGES * 8;                // 9.6 MB worst case

    hipMemsetAsync(ws + zero_base, 0, zero_len, stream);

    proj_kernel<<<(N_NODES + 127) / 128, 512, 0, stream>>>(emb, Ws, bs, Wn, bn, xm);
    flag_kernel<<<(N_QUERY + 255) / 256, 256, 0, stream>>>(query, qmask);
    count_kernel<<<(N_EDGES + 255) / 256, 256, 0, stream>>>(dst, qmask, deg);
    scan1_kernel<<<SCAN_BLOCKS, 256, 0, stream>>>(deg, offs, bsum);
    scan2_kernel<<<1, 512, 0, stream>>>(bsum);
    fill_kernel<<<(N_EDGES + 255) / 256, 256, 0, stream>>>(
        dst, src, edge_w, qmask, offs, bsum, cursor, pairs);
    gather_readout_kernel<<<(N_QUERY + 3) / 4, 256, 0, stream>>>(
        query, deg, offs, bsum, pairs, xm, Wr, br, out);
}